// Round 5
// baseline (733.866 us; speedup 1.0000x reference)
//
#include <hip/hip_runtime.h>
#include <math.h>

constexpr int NB = 8, NC = 256, NE = 512, NH = 64, NW = 64, NHW = NH * NW;
constexpr int STEPS = 6;

typedef short bfrag8 __attribute__((ext_vector_type(8)));   // 8 bf16 in 4 VGPRs
typedef float f32x4 __attribute__((ext_vector_type(4)));

__device__ __forceinline__ float sigm_(float x) { return 1.f / (1.f + expf(-x)); }
__device__ __forceinline__ float gelu_(float x) {
    return 0.5f * x * (1.f + erff(x * 0.70710678118654752f));
}
__device__ __forceinline__ ushort f2bf(float f) {
    unsigned u = __builtin_bit_cast(unsigned, f);
    unsigned r = (u + 0x7fffu + ((u >> 16) & 1u)) >> 16;   // RNE
    return (ushort)r;
}
__device__ __forceinline__ float bf2f(ushort us) {
    return __builtin_bit_cast(float, (unsigned)us << 16);
}
__device__ __forceinline__ void gload16(const void* g, void* l) {
    __builtin_amdgcn_global_load_lds((const __attribute__((address_space(1))) void*)g,
                                     (__attribute__((address_space(3))) void*)l, 16, 0, 0);
}

// ---------- prologue: bf16 transposed weights ----------
__global__ void wt_kernel(const float* __restrict__ w1, const float* __restrict__ w2,
                          ushort* __restrict__ w1t, ushort* __restrict__ w2t) {
    const int bid = blockIdx.x, tid = threadIdx.x;
    if (bid < NE) {                       // w1t[e][c] = w1[c][e]
        w1t[bid * NC + tid] = f2bf(w1[(size_t)tid * NE + bid]);
    } else {                              // w2t[c][e] = w2[e][c]
        const int c = bid - NE;
        for (int e = tid; e < NE; e += 256)
            w2t[c * NE + e] = f2bf(w2[(size_t)e * NC + c]);
    }
}

// ---------- prologue: forcing -> bf16 (same channel-major layout) ----------
__global__ void fconv_kernel(const float* __restrict__ fin, ushort* __restrict__ fout) {
    const size_t i8 = ((size_t)blockIdx.x * 256 + threadIdx.x) * 8;
    const float4 a = *reinterpret_cast<const float4*>(fin + i8);
    const float4 b = *reinterpret_cast<const float4*>(fin + i8 + 4);
    uint4 o;
    o.x = (unsigned)f2bf(a.x) | ((unsigned)f2bf(a.y) << 16);
    o.y = (unsigned)f2bf(a.z) | ((unsigned)f2bf(a.w) << 16);
    o.z = (unsigned)f2bf(b.x) | ((unsigned)f2bf(b.y) << 16);
    o.w = (unsigned)f2bf(b.z) | ((unsigned)f2bf(b.w) << 16);
    *reinterpret_cast<uint4*>(fout + i8) = o;
}

// ---------- prologue: X[m][c] bf16 from u0[b][c][hw] + per-row channel sums ----------
__global__ __launch_bounds__(256) void x0_kernel(const float* __restrict__ u,
                                                 ushort* __restrict__ X,
                                                 float* __restrict__ rowsums) {
    __shared__ ushort xs[64][264];
    const int tid = threadIdx.x;
    const int b = blockIdx.x >> 6, y = blockIdx.x & 63;
    const float* up = u + (size_t)b * NC * NHW + y * NW;
#pragma unroll
    for (int cc = 0; cc < 4; ++cc)
#pragma unroll
        for (int i = 0; i < 16; ++i) {
            const int idx = i * 256 + tid;
            const int c = idx >> 6, x = idx & 63;
            xs[x][cc * 64 + c] = f2bf(up[(size_t)(cc * 64 + c) * NHW + x]);
        }
    __syncthreads();
    ushort* Xp = X + ((size_t)b * NHW + y * NW) * NC;
    const int wv = tid >> 6, lane = tid & 63;
#pragma unroll
    for (int r = 0; r < 16; ++r) {
        const int row = wv * 16 + r;
        *reinterpret_cast<uint2*>(Xp + (size_t)row * NC + lane * 4) =
            *reinterpret_cast<const uint2*>(&xs[row][lane * 4]);
    }
    const float* rp = up + (size_t)tid * NHW;
    float s = 0.f;
#pragma unroll
    for (int x = 0; x < 64; ++x) s += rp[x];
    rowsums[((size_t)b * 64 + y) * NC + tid] = s;
}

// ---------- gated global memory: 3 gates in parallel + fused combine ----------
__global__ __launch_bounds__(768) void gates_kernel(
    const float* __restrict__ rowsums,
    const float* __restrict__ wf, const float* __restrict__ bfv,
    const float* __restrict__ wi, const float* __restrict__ biv,
    const float* __restrict__ wc, const float* __restrict__ bcv,
    float* __restrict__ h, const int first) {
    const int b = blockIdx.x;
    const int tid = threadIdx.x;
    const int g = tid >> 8, c = tid & 255;
    __shared__ float sp[256];
    __shared__ float psum[3][256];
    __shared__ float gf[256], gi[256];
    const int y0 = (g == 0) ? 0 : (g == 1) ? 21 : 42;
    const int y1 = (g == 0) ? 21 : (g == 1) ? 42 : 64;
    const float* rs = rowsums + (size_t)b * 64 * NC + c;
    float s = 0.f;
    for (int y = y0; y < y1; ++y) s += rs[y * NC];
    psum[g][c] = s;
    __syncthreads();
    if (g == 0) sp[c] = (psum[0][c] + psum[1][c] + psum[2][c]) * (1.f / 4096.f);
    __syncthreads();
    const float* W  = (g == 0) ? wf  : (g == 1) ? wi  : wc;
    const float* Bv = (g == 0) ? bfv : (g == 1) ? biv : bcv;
    float a = Bv[c];
#pragma unroll 8
    for (int k = 0; k < 256; ++k) a = fmaf(sp[k], W[k * NC + c], a);
    if (g == 0) gf[c] = sigm_(a);
    else if (g == 1) gi[c] = sigm_(a);
    __syncthreads();
    if (g == 2) {
        const float cc = tanhf(a);
        const float hold = first ? 0.f : h[b * NC + c];
        h[b * NC + c] = hold * gf[c] + gi[c] * cc;
    }
}

// ---------- fully fused step: MLP(GEMM1+GEMM2) + stencil + memory + Euler + RMSNorm ----------
__global__ __launch_bounds__(256, 2) void step_kernel(
    const ushort* __restrict__ Xg, const ushort* __restrict__ w1t,
    const ushort* __restrict__ w2t, const float* __restrict__ b1,
    const float* __restrict__ b2, const float* __restrict__ uin,
    const ushort* __restrict__ forc, const float* __restrict__ dlog,
    const float* __restrict__ hbuf, const float* __restrict__ nsc,
    const float* __restrict__ p_logdt, const float* __restrict__ p_am,
    const float* __restrict__ p_af, const int do_norm,
    float* __restrict__ uout, ushort* __restrict__ Xout,
    float* __restrict__ rowsums) {
    __shared__ __align__(16) char pool[52224];
    ushort* Xs = (ushort*)pool;                 // [64px][256c] swizzled (GEMM phase)
    // Hs dbuf at 32768 + (ec&1)*8192, each [64px][64e] swizzled

    const int tid = threadIdx.x;
    const int wv = tid >> 6, lane = tid & 63;
    const int r16 = lane & 15, kg = lane >> 4;
    const int work = (blockIdx.x & 7) * 64 + (blockIdx.x >> 3);   // XCD swizzle
    const int b = work >> 6, y = work & 63;
    const int m0 = work * 64;

    // ---- stage X tile ----
#pragma unroll
    for (int i = 0; i < 8; ++i) {
        const int idx = i * 256 + tid, row = idx >> 5, s = idx & 31;
        gload16(Xg + (size_t)(m0 + row) * NC + ((s ^ (row & 7)) << 3), Xs + idx * 8);
    }

    // ---- w1 fragments for ec=0 (registers, from L2) ----
    const ushort* w1base = w1t + (size_t)(wv * 16 + r16) * NC + kg * 8;
    bfrag8 w1f[8], w2f[8];
#pragma unroll
    for (int kk = 0; kk < 8; ++kk)
        w1f[kk] = *(const bfrag8*)(w1base + kk * 32);

    f32x4 acc2[4][4];   // [ct c-tile][p px-tile]; wave's c-slice = wv*64
#pragma unroll
    for (int ct = 0; ct < 4; ++ct)
#pragma unroll
        for (int p = 0; p < 4; ++p) acc2[ct][p] = (f32x4){0.f, 0.f, 0.f, 0.f};

    __syncthreads();   // Xs ready

    // ---- e-chunk loop: 1 barrier per chunk ----
    for (int ec = 0; ec < 8; ++ec) {
        // w2 fragments for this chunk (used after the barrier; hides under GEMM1)
#pragma unroll
        for (int ct = 0; ct < 4; ++ct)
#pragma unroll
            for (int kk = 0; kk < 2; ++kk)
                w2f[ct * 2 + kk] = *(const bfrag8*)(w2t
                    + (size_t)(wv * 64 + ct * 16 + r16) * NE + ec * 64 + (kk * 4 + kg) * 8);

        // GEMM1: D1[e][px]; A = w1 regs, B = Xs rows
        f32x4 acc1[4];
#pragma unroll
        for (int p = 0; p < 4; ++p) acc1[p] = (f32x4){0.f, 0.f, 0.f, 0.f};
#pragma unroll
        for (int kk = 0; kk < 8; ++kk) {
            const int g = kk * 4 + kg;
#pragma unroll
            for (int p = 0; p < 4; ++p) {
                const int rb = p * 16 + r16;
                const bfrag8 bb = *(const bfrag8*)(Xs + rb * 256 + ((g ^ (rb & 7)) << 3));
                acc1[p] = __builtin_amdgcn_mfma_f32_16x16x32_bf16(w1f[kk], bb, acc1[p], 0, 0, 0);
            }
        }
        // prefetch w1 for next chunk (hides under GELU + barrier + GEMM2)
        if (ec < 7) {
#pragma unroll
            for (int kk = 0; kk < 8; ++kk)
                w1f[kk] = *(const bfrag8*)(w1base + (size_t)(ec + 1) * 64 * NC + kk * 32);
        }
        // GELU -> Hs[ec&1]; lane holds e = ec*64+wv*16+kg*4+j, px = p*16+r16
        ushort* Hs = (ushort*)(pool + 32768 + (ec & 1) * 8192);
        const float4 b1v = *(const float4*)(b1 + ec * 64 + wv * 16 + kg * 4);
        const float bj[4] = {b1v.x, b1v.y, b1v.z, b1v.w};
#pragma unroll
        for (int p = 0; p < 4; ++p) {
            ushort4 hv;
            hv.x = f2bf(gelu_(acc1[p][0] + bj[0]));
            hv.y = f2bf(gelu_(acc1[p][1] + bj[1]));
            hv.z = f2bf(gelu_(acc1[p][2] + bj[2]));
            hv.w = f2bf(gelu_(acc1[p][3] + bj[3]));
            const int px = p * 16 + r16;
            const int gH = wv * 2 + (kg >> 1);
            *(ushort4*)(Hs + px * 64 + ((gH ^ (px & 7)) << 3) + ((kg & 1) << 2)) = hv;
        }
        __syncthreads();   // Hs[ec&1] visible; also fences Hs reuse 2 chunks later
        // GEMM2: react[c][px] += ; A = w2 regs, B = Hs rows
#pragma unroll
        for (int kk = 0; kk < 2; ++kk) {
            const int g = kk * 4 + kg;
            bfrag8 bfr[4];
#pragma unroll
            for (int p = 0; p < 4; ++p) {
                const int rb = p * 16 + r16;
                bfr[p] = *(const bfrag8*)(Hs + rb * 64 + ((g ^ (rb & 7)) << 3));
            }
#pragma unroll
            for (int ct = 0; ct < 4; ++ct)
#pragma unroll
                for (int p = 0; p < 4; ++p)
                    acc2[ct][p] = __builtin_amdgcn_mfma_f32_16x16x32_bf16(w2f[ct * 2 + kk],
                                                                          bfr[p], acc2[ct][p], 0, 0, 0);
        }
    }

    // ---- epilogue: dump react -> trh (2 halves), stencil + Euler ----
    float* trh = (float*)pool;                     // [128][68] f32
    float* su  = (float*)(pool + 34816);           // [64][68] f32
    const int eg = tid >> 4, pg = tid & 15, x0p = pg * 4;
    const float dt = fminf(fmaxf(expf(p_logdt[0]), 0.01f), 0.3f);
    const float am = p_am[0], afc = p_af[0];
    const float* ub = uin + (size_t)b * NC * NHW;
    const ushort* frow = forc + (size_t)b * NC * NHW + (size_t)y * NW;

    float unew[4][4][4];   // [ch][jc][ip]

#pragma unroll
    for (int h2 = 0; h2 < 2; ++h2) {
        __syncthreads();                 // all GEMM reads done / prev-half trh reads done
        if ((wv >> 1) == h2) {
            // lane holds c = wv*64 + ct*16 + kg*4 + j ; px = p*16 + r16
#pragma unroll
            for (int ct = 0; ct < 4; ++ct)
#pragma unroll
                for (int p = 0; p < 4; ++p)
#pragma unroll
                    for (int j = 0; j < 4; ++j)
                        trh[((wv & 1) * 64 + ct * 16 + kg * 4 + j) * 68 + p * 16 + r16] =
                            acc2[ct][p][j];
        }
#pragma unroll
        for (int chi = 0; chi < 2; ++chi) {
            const int ch = h2 * 2 + chi;
            __syncthreads();             // trh ready / prev su reads done
#pragma unroll
            for (int i = 0; i < 4; ++i) {
                const int idx = i * 256 + tid;
                const int r = idx >> 4, q = (idx & 15) * 4;
                *(float4*)&su[r * 68 + q] =
                    *(const float4*)(ub + (size_t)(ch * 64 + r) * NHW + (size_t)y * NW + q);
            }
            __syncthreads();
#pragma unroll
            for (int jc = 0; jc < 4; ++jc) {
                const int cc = eg * 4 + jc;
                const int c = ch * 64 + cc;
                const float co0 = 0.25f * sigm_(dlog[c]);
                const float co1 = 0.25f * sigm_(dlog[NC + c]);
                const float co2 = 0.25f * sigm_(dlog[2 * NC + c]);
                const float hterm = am * hbuf[b * NC + c];
                const float b2v = b2[c];
                const float* up = ub + (size_t)c * NHW;

                float ym[6][4];
                const int dy[6] = {-1, 1, -2, 2, -4, 4};
#pragma unroll
                for (int n = 0; n < 6; ++n) {
                    int ry = y + dy[n];
                    ry = ry < 0 ? -ry : (ry > 63 ? 126 - ry : ry);
                    const float4 t = *reinterpret_cast<const float4*>(up + (size_t)ry * NW + x0p);
                    ym[n][0] = t.x; ym[n][1] = t.y; ym[n][2] = t.z; ym[n][3] = t.w;
                }
                const uint2 fr = *reinterpret_cast<const uint2*>(frow + (size_t)c * NHW + x0p);
                float fv[4];
                fv[0] = bf2f((ushort)(fr.x & 0xffff));
                fv[1] = bf2f((ushort)(fr.x >> 16));
                fv[2] = bf2f((ushort)(fr.y & 0xffff));
                fv[3] = bf2f((ushort)(fr.y >> 16));
                const f32x4 rv = *reinterpret_cast<const f32x4*>(&trh[(chi * 64 + cc) * 68 + x0p]);
#pragma unroll
                for (int ip = 0; ip < 4; ++ip) {
                    const int x = x0p + ip;
                    const float uc = su[cc * 68 + x];
                    int xm, xp2;
                    float dsum = 0.f, lap;
                    xm = x - 1; xm = xm < 0 ? -xm : xm;
                    xp2 = x + 1; xp2 = xp2 > 63 ? 126 - xp2 : xp2;
                    lap = su[cc * 68 + xm] + su[cc * 68 + xp2] + ym[0][ip] + ym[1][ip] - 4.f * uc;
                    dsum = fmaf(co0, lap, dsum);
                    xm = x - 2; xm = xm < 0 ? -xm : xm;
                    xp2 = x + 2; xp2 = xp2 > 63 ? 126 - xp2 : xp2;
                    lap = su[cc * 68 + xm] + su[cc * 68 + xp2] + ym[2][ip] + ym[3][ip] - 4.f * uc;
                    dsum = fmaf(co1, lap, dsum);
                    xm = x - 4; xm = xm < 0 ? -xm : xm;
                    xp2 = x + 4; xp2 = xp2 > 63 ? 126 - xp2 : xp2;
                    lap = su[cc * 68 + xm] + su[cc * 68 + xp2] + ym[4][ip] + ym[5][ip] - 4.f * uc;
                    dsum = fmaf(co2, lap, dsum);

                    const float du_ = dsum + rv[ip] + b2v + hterm + afc * fv[ip];
                    unew[ch][jc][ip] = uc + dt * du_;
                }
            }
        }
    }

    // ---- RMSNorm over channels ----
    float* redc = (float*)(pool + 34816);          // [16][68] (overlays su)
    float* inv64p = (float*)pool;                  // [64] (overlays dead trh)
    if (do_norm) {
        float ps[4] = {0.f, 0.f, 0.f, 0.f};
#pragma unroll
        for (int ch = 0; ch < 4; ++ch)
#pragma unroll
            for (int jc = 0; jc < 4; ++jc)
#pragma unroll
                for (int ip = 0; ip < 4; ++ip)
                    ps[ip] = fmaf(unew[ch][jc][ip], unew[ch][jc][ip], ps[ip]);
        __syncthreads();
        *reinterpret_cast<f32x4*>(&redc[eg * 68 + x0p]) = (f32x4){ps[0], ps[1], ps[2], ps[3]};
        __syncthreads();
        if (tid < 64) {
            float s = 0.f;
#pragma unroll
            for (int g = 0; g < 16; ++g) s += redc[g * 68 + tid];
            inv64p[tid] = 1.f / (sqrtf(s) * 0.0625f + 1e-6f);
        }
    }
    __syncthreads();   // inv64 ready; redc/su/trh dead

    // ---- store u_new (fp32, channel-major) + Xout (bf16, pixel-major, direct) ----
    float* sums = (float*)(pool + 34816);          // [256][17]
    float persum[4][4];
    float* uob = uout + (size_t)b * NC * NHW + (size_t)y * NW;
#pragma unroll
    for (int ch = 0; ch < 4; ++ch) {
        float vsc[4][4];   // [jc][ip]
#pragma unroll
        for (int jc = 0; jc < 4; ++jc) {
            const int cc = eg * 4 + jc;
            const int c = ch * 64 + cc;
            const float ns = do_norm ? nsc[c] : 1.f;
#pragma unroll
            for (int ip = 0; ip < 4; ++ip) {
                float v = unew[ch][jc][ip];
                if (do_norm) v *= inv64p[x0p + ip] * ns;
                vsc[jc][ip] = v;
            }
            persum[ch][jc] = vsc[jc][0] + vsc[jc][1] + vsc[jc][2] + vsc[jc][3];
            float4 o; o.x = vsc[jc][0]; o.y = vsc[jc][1]; o.z = vsc[jc][2]; o.w = vsc[jc][3];
            *reinterpret_cast<float4*>(uob + (size_t)c * NHW + x0p) = o;
        }
#pragma unroll
        for (int ip = 0; ip < 4; ++ip) {
            ushort4 xv;
            xv.x = f2bf(vsc[0][ip]);
            xv.y = f2bf(vsc[1][ip]);
            xv.z = f2bf(vsc[2][ip]);
            xv.w = f2bf(vsc[3][ip]);
            *reinterpret_cast<ushort4*>(Xout + (size_t)(m0 + x0p + ip) * NC + ch * 64 + eg * 4) = xv;
        }
    }
#pragma unroll
    for (int ch = 0; ch < 4; ++ch)
#pragma unroll
        for (int jc = 0; jc < 4; ++jc)
            sums[(ch * 64 + eg * 4 + jc) * 17 + pg] = persum[ch][jc];
    __syncthreads();
    {
        float s = 0.f;
#pragma unroll
        for (int g = 0; g < 16; ++g) s += sums[tid * 17 + g];
        rowsums[((size_t)b * 64 + y) * NC + tid] = s;
    }
}

extern "C" void kernel_launch(void* const* d_in, const int* in_sizes, int n_in,
                              void* d_out, int out_size, void* d_ws, size_t ws_size,
                              hipStream_t stream) {
    (void)in_sizes; (void)n_in; (void)out_size; (void)ws_size;
    const float* u0      = (const float*)d_in[0];
    const float* forcing = (const float*)d_in[1];
    const float* dlog    = (const float*)d_in[2];
    const float* w1      = (const float*)d_in[3];
    const float* b1      = (const float*)d_in[4];
    const float* w2      = (const float*)d_in[5];
    const float* b2      = (const float*)d_in[6];
    const float* wf      = (const float*)d_in[7];
    const float* bfv     = (const float*)d_in[8];
    const float* wi      = (const float*)d_in[9];
    const float* biv     = (const float*)d_in[10];
    const float* wc      = (const float*)d_in[11];
    const float* bcv     = (const float*)d_in[12];
    const float* nsc     = (const float*)d_in[13];
    const float* p_logdt = (const float*)d_in[14];
    const float* p_am    = (const float*)d_in[15];
    const float* p_af    = (const float*)d_in[16];

    float* uout = (float*)d_out;

    char* w = (char*)d_ws;
    float*  uA     = (float*)w;   w += (size_t)NB * NC * NHW * 4;   // 33.5 MB
    ushort* X      = (ushort*)w;  w += (size_t)NB * NHW * NC * 2;   // 16.8 MB
    ushort* forc   = (ushort*)w;  w += (size_t)NB * NC * NHW * 2;   // 16.8 MB
    ushort* w1t    = (ushort*)w;  w += (size_t)NE * NC * 2;
    ushort* w2t    = (ushort*)w;  w += (size_t)NC * NE * 2;
    float* rowsums = (float*)w;   w += (size_t)NB * NH * NC * 4;    // 512 KB
    float* hbuf    = (float*)w;   w += (size_t)NB * NC * 4;

    wt_kernel<<<768, 256, 0, stream>>>(w1, w2, w1t, w2t);
    fconv_kernel<<<4096, 256, 0, stream>>>(forcing, forc);
    x0_kernel<<<NB * NH, 256, 0, stream>>>(u0, X, rowsums);

    const float* src = u0;
    for (int t = 0; t < STEPS; ++t) {
        float* dst = (t & 1) ? uout : uA;    // t=5 -> uout
        gates_kernel<<<NB, 768, 0, stream>>>(rowsums, wf, bfv, wi, biv, wc, bcv, hbuf, t == 0);
        step_kernel<<<NB * NH, 256, 0, stream>>>(X, w1t, w2t, b1, b2, src, forc, dlog,
                                                 hbuf, nsc, p_logdt, p_am, p_af,
                                                 ((t + 1) % 2) == 0, dst, X, rowsums);
        src = dst;
    }
}

// Round 6
// 590.615 us; speedup vs baseline: 1.2425x; 1.2425x over previous
//
#include <hip/hip_runtime.h>
#include <math.h>

constexpr int NB = 8, NC = 256, NE = 512, NH = 64, NW = 64, NHW = NH * NW;
constexpr int STEPS = 6;

typedef short bfrag8 __attribute__((ext_vector_type(8)));   // 8 bf16 in 4 VGPRs
typedef float f32x4 __attribute__((ext_vector_type(4)));

__device__ __forceinline__ float sigm_(float x) { return 1.f / (1.f + expf(-x)); }
__device__ __forceinline__ float gelu_(float x) {
    return 0.5f * x * (1.f + erff(x * 0.70710678118654752f));
}
__device__ __forceinline__ ushort f2bf(float f) {
    unsigned u = __builtin_bit_cast(unsigned, f);
    unsigned r = (u + 0x7fffu + ((u >> 16) & 1u)) >> 16;   // RNE
    return (ushort)r;
}
__device__ __forceinline__ float bf2f(ushort us) {
    return __builtin_bit_cast(float, (unsigned)us << 16);
}
__device__ __forceinline__ void gload16(const void* g, void* l) {
    __builtin_amdgcn_global_load_lds((const __attribute__((address_space(1))) void*)g,
                                     (__attribute__((address_space(3))) void*)l, 16, 0, 0);
}

// ---------- prologue: bf16 transposed weights ----------
__global__ void wt_kernel(const float* __restrict__ w1, const float* __restrict__ w2,
                          ushort* __restrict__ w1t, ushort* __restrict__ w2t) {
    const int bid = blockIdx.x, tid = threadIdx.x;
    if (bid < NE) {                       // w1t[e][c] = w1[c][e]
        w1t[bid * NC + tid] = f2bf(w1[(size_t)tid * NE + bid]);
    } else {                              // w2t[c][e] = w2[e][c]
        const int c = bid - NE;
        for (int e = tid; e < NE; e += 256)
            w2t[c * NE + e] = f2bf(w2[(size_t)e * NC + c]);
    }
}

// ---------- prologue: forcing -> bf16 ----------
__global__ void fconv_kernel(const float* __restrict__ fin, ushort* __restrict__ fout) {
    const size_t i8 = ((size_t)blockIdx.x * 256 + threadIdx.x) * 8;
    const float4 a = *reinterpret_cast<const float4*>(fin + i8);
    const float4 b = *reinterpret_cast<const float4*>(fin + i8 + 4);
    uint4 o;
    o.x = (unsigned)f2bf(a.x) | ((unsigned)f2bf(a.y) << 16);
    o.y = (unsigned)f2bf(a.z) | ((unsigned)f2bf(a.w) << 16);
    o.z = (unsigned)f2bf(b.x) | ((unsigned)f2bf(b.y) << 16);
    o.w = (unsigned)f2bf(b.z) | ((unsigned)f2bf(b.w) << 16);
    *reinterpret_cast<uint4*>(fout + i8) = o;
}

// ---------- prologue: X[m][c] bf16 + per-row channel sums ----------
__global__ __launch_bounds__(256) void x0_kernel(const float* __restrict__ u,
                                                 ushort* __restrict__ X,
                                                 float* __restrict__ rowsums) {
    __shared__ ushort xs[64][264];
    const int tid = threadIdx.x;
    const int b = blockIdx.x >> 6, y = blockIdx.x & 63;
    const float* up = u + (size_t)b * NC * NHW + y * NW;
#pragma unroll
    for (int cc = 0; cc < 4; ++cc)
#pragma unroll
        for (int i = 0; i < 16; ++i) {
            const int idx = i * 256 + tid;
            const int c = idx >> 6, x = idx & 63;
            xs[x][cc * 64 + c] = f2bf(up[(size_t)(cc * 64 + c) * NHW + x]);
        }
    __syncthreads();
    ushort* Xp = X + ((size_t)b * NHW + y * NW) * NC;
    const int wv = tid >> 6, lane = tid & 63;
#pragma unroll
    for (int r = 0; r < 16; ++r) {
        const int row = wv * 16 + r;
        *reinterpret_cast<uint2*>(Xp + (size_t)row * NC + lane * 4) =
            *reinterpret_cast<const uint2*>(&xs[row][lane * 4]);
    }
    const float* rp = up + (size_t)tid * NHW;
    float s = 0.f;
#pragma unroll
    for (int x = 0; x < 64; ++x) s += rp[x];
    rowsums[((size_t)b * 64 + y) * NC + tid] = s;
}

// ---------- gated global memory: 3 gates in parallel ----------
__global__ __launch_bounds__(768) void gates_kernel(
    const float* __restrict__ rowsums,
    const float* __restrict__ wf, const float* __restrict__ bfv,
    const float* __restrict__ wi, const float* __restrict__ biv,
    const float* __restrict__ wc, const float* __restrict__ bcv,
    float* __restrict__ h, const int first) {
    const int b = blockIdx.x;
    const int tid = threadIdx.x;
    const int g = tid >> 8, c = tid & 255;
    __shared__ float sp[256];
    __shared__ float psum[3][256];
    __shared__ float gf[256], gi[256];
    const int y0 = (g == 0) ? 0 : (g == 1) ? 21 : 42;
    const int y1 = (g == 0) ? 21 : (g == 1) ? 42 : 64;
    const float* rs = rowsums + (size_t)b * 64 * NC + c;
    float s = 0.f;
    for (int y = y0; y < y1; ++y) s += rs[y * NC];
    psum[g][c] = s;
    __syncthreads();
    if (g == 0) sp[c] = (psum[0][c] + psum[1][c] + psum[2][c]) * (1.f / 4096.f);
    __syncthreads();
    const float* W  = (g == 0) ? wf  : (g == 1) ? wi  : wc;
    const float* Bv = (g == 0) ? bfv : (g == 1) ? biv : bcv;
    float a = Bv[c];
#pragma unroll 8
    for (int k = 0; k < 256; ++k) a = fmaf(sp[k], W[k * NC + c], a);
    if (g == 0) gf[c] = sigm_(a);
    else if (g == 1) gi[c] = sigm_(a);
    __syncthreads();
    if (g == 2) {
        const float cc = tanhf(a);
        const float hold = first ? 0.f : h[b * NC + c];
        h[b * NC + c] = hold * gf[c] + gi[c] * cc;
    }
}

// ---------- fused step: 512 threads (8 waves), 16 waves/CU ----------
__global__ __launch_bounds__(512, 4) void step_kernel(
    const ushort* __restrict__ Xg, const ushort* __restrict__ w1t,
    const ushort* __restrict__ w2t, const float* __restrict__ b1,
    const float* __restrict__ b2, const float* __restrict__ uin,
    const ushort* __restrict__ forc, const float* __restrict__ dlog,
    const float* __restrict__ hbuf, const float* __restrict__ nsc,
    const float* __restrict__ p_logdt, const float* __restrict__ p_am,
    const float* __restrict__ p_af, const int do_norm,
    float* __restrict__ uout, ushort* __restrict__ Xout,
    float* __restrict__ rowsums) {
    __shared__ __align__(16) char pool[73728];
    ushort* Xs = (ushort*)pool;                 // [64px][256c] swizzled
    ushort* Wb = (ushort*)(pool + 32768);       // w1 [64e][256c] / w2 [256c][64e]
    ushort* Hs = (ushort*)(pool + 65536);       // [64px][64e] swizzled

    const int tid = threadIdx.x;
    const int wv = tid >> 6, lane = tid & 63;
    const int r16 = lane & 15, kg = lane >> 4;
    const int work = (blockIdx.x & 7) * 64 + (blockIdx.x >> 3);   // XCD swizzle
    const int b = work >> 6, y = work & 63;
    const int m0 = work * 64;

    // ---- stage X tile ----
#pragma unroll
    for (int i = 0; i < 4; ++i) {
        const int idx = i * 512 + tid, row = idx >> 5, s = idx & 31;
        gload16(Xg + (size_t)(m0 + row) * NC + ((s ^ (row & 7)) << 3), Xs + idx * 8);
    }

    f32x4 acc2[2][4];   // [ct][p]; wave's c-slice = wv*32
#pragma unroll
    for (int ct = 0; ct < 2; ++ct)
#pragma unroll
        for (int p = 0; p < 4; ++p) acc2[ct][p] = (f32x4){0.f, 0.f, 0.f, 0.f};

    const int epart = wv >> 1, pxh = wv & 1;   // GEMM1 wave roles

    for (int ec = 0; ec < 8; ++ec) {
        __syncthreads();   // A: prev G2 reads of Wb/Hs done
#pragma unroll
        for (int i = 0; i < 4; ++i) {          // stage w1 chunk [64e][256c]
            const int idx = i * 512 + tid, row = idx >> 5, s = idx & 31;
            gload16(w1t + (size_t)(ec * 64 + row) * NC + ((s ^ (row & 7)) << 3),
                    Wb + idx * 8);
        }
        __syncthreads();   // B: w1 (and Xs) ready
        // GEMM1: D1[e][px]; wave = (epart, pxh)
        f32x4 acc1[2];
#pragma unroll
        for (int p = 0; p < 2; ++p) acc1[p] = (f32x4){0.f, 0.f, 0.f, 0.f};
#pragma unroll
        for (int kk = 0; kk < 8; ++kk) {
            const int g = kk * 4 + kg;
            const int rowA = epart * 16 + r16;
            const bfrag8 a = *(const bfrag8*)(Wb + rowA * 256 + ((g ^ (rowA & 7)) << 3));
#pragma unroll
            for (int p = 0; p < 2; ++p) {
                const int rowB = pxh * 32 + p * 16 + r16;
                const bfrag8 bb = *(const bfrag8*)(Xs + rowB * 256 + ((g ^ (rowB & 7)) << 3));
                acc1[p] = __builtin_amdgcn_mfma_f32_16x16x32_bf16(a, bb, acc1[p], 0, 0, 0);
            }
        }
        __syncthreads();   // C: all waves done reading Wb(w1)
        // GELU -> Hs[px][e]; lane e = epart*16+kg*4+j, px = pxh*32+p*16+r16
        const float4 b1v = *(const float4*)(b1 + ec * 64 + epart * 16 + kg * 4);
        const float bj[4] = {b1v.x, b1v.y, b1v.z, b1v.w};
#pragma unroll
        for (int p = 0; p < 2; ++p) {
            ushort4 hv;
            hv.x = f2bf(gelu_(acc1[p][0] + bj[0]));
            hv.y = f2bf(gelu_(acc1[p][1] + bj[1]));
            hv.z = f2bf(gelu_(acc1[p][2] + bj[2]));
            hv.w = f2bf(gelu_(acc1[p][3] + bj[3]));
            const int px = pxh * 32 + p * 16 + r16;
            const int gr = epart * 2 + (kg >> 1);
            *(ushort4*)(Hs + px * 64 + ((gr ^ (px & 7)) << 3) + ((kg & 1) << 2)) = hv;
        }
#pragma unroll
        for (int i = 0; i < 4; ++i) {          // stage w2 chunk [256c][64e]
            const int idx = i * 512 + tid, row = idx >> 3, s = idx & 7;
            gload16(w2t + (size_t)row * NE + ec * 64 + ((s ^ (row & 7)) << 3),
                    Wb + idx * 8);
        }
        __syncthreads();   // D: w2 + Hs ready
        // GEMM2: react[c][px]; wave owns c = wv*32 + ct*16
#pragma unroll
        for (int kk = 0; kk < 2; ++kk) {
            const int g = kk * 4 + kg;
            bfrag8 bfr[4];
#pragma unroll
            for (int p = 0; p < 4; ++p) {
                const int rowB = p * 16 + r16;
                bfr[p] = *(const bfrag8*)(Hs + rowB * 64 + ((g ^ (rowB & 7)) << 3));
            }
#pragma unroll
            for (int ct = 0; ct < 2; ++ct) {
                const int rowA = wv * 32 + ct * 16 + r16;
                const bfrag8 a = *(const bfrag8*)(Wb + rowA * 64 + ((g ^ (rowA & 7)) << 3));
#pragma unroll
                for (int p = 0; p < 4; ++p)
                    acc2[ct][p] = __builtin_amdgcn_mfma_f32_16x16x32_bf16(a, bfr[p],
                                                                          acc2[ct][p], 0, 0, 0);
            }
        }
    }

    // ---- epilogue ----
    float* trh = (float*)pool;                     // [128][68] f32 (half of c)
    float* su  = (float*)(pool + 34816);           // [128][68] f32 (u_old half)
    const int eg2 = tid >> 4, pg = tid & 15, x0p = pg * 4;
    const float dt = fminf(fmaxf(expf(p_logdt[0]), 0.01f), 0.3f);
    const float am = p_am[0], afc = p_af[0];
    const float* ub = uin + (size_t)b * NC * NHW;
    const ushort* frow = forc + (size_t)b * NC * NHW + (size_t)y * NW;

    float unew[2][4][4];   // [h2][jc][ip]

#pragma unroll
    for (int h2 = 0; h2 < 2; ++h2) {
        __syncthreads();   // GEMM done / prev-half trh+su reads done
        if ((wv >> 2) == h2) {
            // lane: c_rel = (wv&3)*32 + ct*16 + kg*4 + j ; px = p*16 + r16
#pragma unroll
            for (int ct = 0; ct < 2; ++ct)
#pragma unroll
                for (int p = 0; p < 4; ++p)
#pragma unroll
                    for (int j = 0; j < 4; ++j)
                        trh[((wv & 3) * 32 + ct * 16 + kg * 4 + j) * 68 + p * 16 + r16] =
                            acc2[ct][p][j];
        }
#pragma unroll
        for (int i = 0; i < 4; ++i) {   // stage u_old half [128c][64px]
            const int idx = i * 512 + tid;
            const int r = idx >> 4, q = (idx & 15) * 4;
            *(float4*)&su[r * 68 + q] =
                *(const float4*)(ub + (size_t)(h2 * 128 + r) * NHW + (size_t)y * NW + q);
        }
        __syncthreads();   // trh + su ready
#pragma unroll
        for (int jc = 0; jc < 4; ++jc) {
            const int crel = eg2 * 4 + jc;
            const int c = h2 * 128 + crel;
            const float co0 = 0.25f * sigm_(dlog[c]);
            const float co1 = 0.25f * sigm_(dlog[NC + c]);
            const float co2 = 0.25f * sigm_(dlog[2 * NC + c]);
            const float hterm = am * hbuf[b * NC + c];
            const float b2v = b2[c];
            const float* up = ub + (size_t)c * NHW;

            float ym[6][4];
            const int dy[6] = {-1, 1, -2, 2, -4, 4};
#pragma unroll
            for (int n = 0; n < 6; ++n) {
                int ry = y + dy[n];
                ry = ry < 0 ? -ry : (ry > 63 ? 126 - ry : ry);
                const float4 t = *reinterpret_cast<const float4*>(up + (size_t)ry * NW + x0p);
                ym[n][0] = t.x; ym[n][1] = t.y; ym[n][2] = t.z; ym[n][3] = t.w;
            }
            const uint2 fr = *reinterpret_cast<const uint2*>(frow + (size_t)c * NHW + x0p);
            float fv[4];
            fv[0] = bf2f((ushort)(fr.x & 0xffff));
            fv[1] = bf2f((ushort)(fr.x >> 16));
            fv[2] = bf2f((ushort)(fr.y & 0xffff));
            fv[3] = bf2f((ushort)(fr.y >> 16));
            const f32x4 rv = *reinterpret_cast<const f32x4*>(&trh[crel * 68 + x0p]);
#pragma unroll
            for (int ip = 0; ip < 4; ++ip) {
                const int x = x0p + ip;
                const float uc = su[crel * 68 + x];
                int xm, xp2;
                float dsum = 0.f, lap;
                xm = x - 1; xm = xm < 0 ? -xm : xm;
                xp2 = x + 1; xp2 = xp2 > 63 ? 126 - xp2 : xp2;
                lap = su[crel * 68 + xm] + su[crel * 68 + xp2] + ym[0][ip] + ym[1][ip] - 4.f * uc;
                dsum = fmaf(co0, lap, dsum);
                xm = x - 2; xm = xm < 0 ? -xm : xm;
                xp2 = x + 2; xp2 = xp2 > 63 ? 126 - xp2 : xp2;
                lap = su[crel * 68 + xm] + su[crel * 68 + xp2] + ym[2][ip] + ym[3][ip] - 4.f * uc;
                dsum = fmaf(co1, lap, dsum);
                xm = x - 4; xm = xm < 0 ? -xm : xm;
                xp2 = x + 4; xp2 = xp2 > 63 ? 126 - xp2 : xp2;
                lap = su[crel * 68 + xm] + su[crel * 68 + xp2] + ym[4][ip] + ym[5][ip] - 4.f * uc;
                dsum = fmaf(co2, lap, dsum);

                const float du_ = dsum + rv[ip] + b2v + hterm + afc * fv[ip];
                unew[h2][jc][ip] = uc + dt * du_;
            }
        }
    }
    __syncthreads();   // trh/su dead

    // ---- RMSNorm ----
    float* redc   = (float*)(pool + 34816);        // [32][68]
    float* inv64p = (float*)(pool + 43520);        // [64]
    if (do_norm) {
        float ps[4] = {0.f, 0.f, 0.f, 0.f};
#pragma unroll
        for (int h2 = 0; h2 < 2; ++h2)
#pragma unroll
            for (int jc = 0; jc < 4; ++jc)
#pragma unroll
                for (int ip = 0; ip < 4; ++ip)
                    ps[ip] = fmaf(unew[h2][jc][ip], unew[h2][jc][ip], ps[ip]);
        *reinterpret_cast<f32x4*>(&redc[eg2 * 68 + x0p]) = (f32x4){ps[0], ps[1], ps[2], ps[3]};
        __syncthreads();
        if (tid < 64) {
            float s = 0.f;
#pragma unroll
            for (int g = 0; g < 32; ++g) s += redc[g * 68 + tid];
            inv64p[tid] = 1.f / (sqrtf(s) * 0.0625f + 1e-6f);
        }
    }
    __syncthreads();   // inv64 ready; trh region free for xs

    // ---- store u_new + LDS transpose for Xout + rowsums ----
    ushort* xs = (ushort*)pool;                    // [64][270] ushort (34560 B)
    float* sums = (float*)(pool + 52224);          // [256][17] (ends 69632)
    float persum[2][4];
    float* uob = uout + (size_t)b * NC * NHW + (size_t)y * NW;
#pragma unroll
    for (int h2 = 0; h2 < 2; ++h2) {
        float vsc[4][4];   // [jc][ip]
#pragma unroll
        for (int jc = 0; jc < 4; ++jc) {
            const int c = h2 * 128 + eg2 * 4 + jc;
            const float ns = do_norm ? nsc[c] : 1.f;
#pragma unroll
            for (int ip = 0; ip < 4; ++ip) {
                float v = unew[h2][jc][ip];
                if (do_norm) v *= inv64p[x0p + ip] * ns;
                vsc[jc][ip] = v;
            }
            persum[h2][jc] = vsc[jc][0] + vsc[jc][1] + vsc[jc][2] + vsc[jc][3];
            float4 o; o.x = vsc[jc][0]; o.y = vsc[jc][1]; o.z = vsc[jc][2]; o.w = vsc[jc][3];
            *reinterpret_cast<float4*>(uob + (size_t)c * NHW + x0p) = o;
        }
#pragma unroll
        for (int ip = 0; ip < 4; ++ip) {
            ushort4 xv;
            xv.x = f2bf(vsc[0][ip]);
            xv.y = f2bf(vsc[1][ip]);
            xv.z = f2bf(vsc[2][ip]);
            xv.w = f2bf(vsc[3][ip]);
            *(ushort4*)(xs + (x0p + ip) * 270 + h2 * 128 + eg2 * 4) = xv;
        }
    }
#pragma unroll
    for (int h2 = 0; h2 < 2; ++h2)
#pragma unroll
        for (int jc = 0; jc < 4; ++jc)
            sums[(h2 * 128 + eg2 * 4 + jc) * 17 + pg] = persum[h2][jc];
    __syncthreads();   // xs + sums ready
    ushort* Xp = Xout + (size_t)m0 * NC;
#pragma unroll
    for (int r = 0; r < 8; ++r) {
        const int row = wv * 8 + r;
        *reinterpret_cast<uint2*>(Xp + (size_t)row * NC + lane * 4) =
            *reinterpret_cast<const uint2*>(&xs[row * 270 + lane * 4]);
    }
    if (tid < 256) {
        float s = 0.f;
#pragma unroll
        for (int g = 0; g < 16; ++g) s += sums[tid * 17 + g];
        rowsums[((size_t)b * 64 + y) * NC + tid] = s;
    }
}

extern "C" void kernel_launch(void* const* d_in, const int* in_sizes, int n_in,
                              void* d_out, int out_size, void* d_ws, size_t ws_size,
                              hipStream_t stream) {
    (void)in_sizes; (void)n_in; (void)out_size; (void)ws_size;
    const float* u0      = (const float*)d_in[0];
    const float* forcing = (const float*)d_in[1];
    const float* dlog    = (const float*)d_in[2];
    const float* w1      = (const float*)d_in[3];
    const float* b1      = (const float*)d_in[4];
    const float* w2      = (const float*)d_in[5];
    const float* b2      = (const float*)d_in[6];
    const float* wf      = (const float*)d_in[7];
    const float* bfv     = (const float*)d_in[8];
    const float* wi      = (const float*)d_in[9];
    const float* biv     = (const float*)d_in[10];
    const float* wc      = (const float*)d_in[11];
    const float* bcv     = (const float*)d_in[12];
    const float* nsc     = (const float*)d_in[13];
    const float* p_logdt = (const float*)d_in[14];
    const float* p_am    = (const float*)d_in[15];
    const float* p_af    = (const float*)d_in[16];

    float* uout = (float*)d_out;

    char* w = (char*)d_ws;
    float*  uA     = (float*)w;   w += (size_t)NB * NC * NHW * 4;   // 33.5 MB
    ushort* X      = (ushort*)w;  w += (size_t)NB * NHW * NC * 2;   // 16.8 MB
    ushort* forc   = (ushort*)w;  w += (size_t)NB * NC * NHW * 2;   // 16.8 MB
    ushort* w1t    = (ushort*)w;  w += (size_t)NE * NC * 2;
    ushort* w2t    = (ushort*)w;  w += (size_t)NC * NE * 2;
    float* rowsums = (float*)w;   w += (size_t)NB * NH * NC * 4;    // 512 KB
    float* hbuf    = (float*)w;   w += (size_t)NB * NC * 4;

    wt_kernel<<<768, 256, 0, stream>>>(w1, w2, w1t, w2t);
    fconv_kernel<<<4096, 256, 0, stream>>>(forcing, forc);
    x0_kernel<<<NB * NH, 256, 0, stream>>>(u0, X, rowsums);

    const float* src = u0;
    for (int t = 0; t < STEPS; ++t) {
        float* dst = (t & 1) ? uout : uA;    // t=5 -> uout
        gates_kernel<<<NB, 768, 0, stream>>>(rowsums, wf, bfv, wi, biv, wc, bcv, hbuf, t == 0);
        step_kernel<<<NB * NH, 512, 0, stream>>>(X, w1t, w2t, b1, b2, src, forc, dlog,
                                                 hbuf, nsc, p_logdt, p_am, p_af,
                                                 ((t + 1) % 2) == 0, dst, X, rowsums);
        src = dst;
    }
}

// Round 8
// 576.460 us; speedup vs baseline: 1.2731x; 1.0246x over previous
//
#include <hip/hip_runtime.h>
#include <math.h>

constexpr int NB = 8, NC = 256, NE = 512, NH = 64, NW = 64, NHW = NH * NW;
constexpr int STEPS = 6;

typedef short bfrag8 __attribute__((ext_vector_type(8)));   // 8 bf16 in 4 VGPRs
typedef float f32x4 __attribute__((ext_vector_type(4)));

__device__ __forceinline__ float sigm_(float x) { return 1.f / (1.f + expf(-x)); }
// tanh-form GELU, overflow-safe: x * sigmoid(1.5957691(x + 0.044715 x^3))
__device__ __forceinline__ float gelu_(float x) {
    const float t2 = fmaf(0.0713548162f * x, x * x, 1.5957691216f * x);
    return x / (1.f + __expf(-t2));
}
__device__ __forceinline__ ushort f2bf(float f) {
    unsigned u = __builtin_bit_cast(unsigned, f);
    unsigned r = (u + 0x7fffu + ((u >> 16) & 1u)) >> 16;   // RNE
    return (ushort)r;
}
__device__ __forceinline__ float bf2f(ushort us) {
    return __builtin_bit_cast(float, (unsigned)us << 16);
}
__device__ __forceinline__ void gload16(const void* g, void* l) {
    __builtin_amdgcn_global_load_lds((const __attribute__((address_space(1))) void*)g,
                                     (__attribute__((address_space(3))) void*)l, 16, 0, 0);
}

// ---------- prologue: bf16 transposed weights + stencil coefficients ----------
__global__ void wt_kernel(const float* __restrict__ w1, const float* __restrict__ w2,
                          const float* __restrict__ dlog,
                          ushort* __restrict__ w1t, ushort* __restrict__ w2t,
                          float* __restrict__ dcoef) {
    const int bid = blockIdx.x, tid = threadIdx.x;
    if (bid < NE) {                       // w1t[e][c] = w1[c][e]
        w1t[bid * NC + tid] = f2bf(w1[(size_t)tid * NE + bid]);
    } else if (bid < NE + NC) {           // w2t[c][e] = w2[e][c]
        const int c = bid - NE;
        for (int e = tid; e < NE; e += 256)
            w2t[c * NE + e] = f2bf(w2[(size_t)e * NC + c]);
    } else {
#pragma unroll
        for (int i = 0; i < 3; ++i)
            dcoef[i * NC + tid] = 0.25f * sigm_(dlog[i * NC + tid]);
    }
}

// ---------- prologue: forcing -> bf16 ----------
__global__ void fconv_kernel(const float* __restrict__ fin, ushort* __restrict__ fout) {
    const size_t i8 = ((size_t)blockIdx.x * 256 + threadIdx.x) * 8;
    const float4 a = *reinterpret_cast<const float4*>(fin + i8);
    const float4 b = *reinterpret_cast<const float4*>(fin + i8 + 4);
    uint4 o;
    o.x = (unsigned)f2bf(a.x) | ((unsigned)f2bf(a.y) << 16);
    o.y = (unsigned)f2bf(a.z) | ((unsigned)f2bf(a.w) << 16);
    o.z = (unsigned)f2bf(b.x) | ((unsigned)f2bf(b.y) << 16);
    o.w = (unsigned)f2bf(b.z) | ((unsigned)f2bf(b.w) << 16);
    *reinterpret_cast<uint4*>(fout + i8) = o;
}

// ---------- prologue: X[m][c] bf16 + per-row channel sums ----------
__global__ __launch_bounds__(256) void x0_kernel(const float* __restrict__ u,
                                                 ushort* __restrict__ X,
                                                 float* __restrict__ rowsums) {
    __shared__ ushort xs[64][264];
    const int tid = threadIdx.x;
    const int b = blockIdx.x >> 6, y = blockIdx.x & 63;
    const float* up = u + (size_t)b * NC * NHW + y * NW;
#pragma unroll
    for (int cc = 0; cc < 4; ++cc)
#pragma unroll
        for (int i = 0; i < 16; ++i) {
            const int idx = i * 256 + tid;
            const int c = idx >> 6, x = idx & 63;
            xs[x][cc * 64 + c] = f2bf(up[(size_t)(cc * 64 + c) * NHW + x]);
        }
    __syncthreads();
    ushort* Xp = X + ((size_t)b * NHW + y * NW) * NC;
    const int wv = tid >> 6, lane = tid & 63;
#pragma unroll
    for (int r = 0; r < 16; ++r) {
        const int row = wv * 16 + r;
        *reinterpret_cast<uint2*>(Xp + (size_t)row * NC + lane * 4) =
            *reinterpret_cast<const uint2*>(&xs[row][lane * 4]);
    }
    const float* rp = up + (size_t)tid * NHW;
    float s = 0.f;
#pragma unroll
    for (int x = 0; x < 64; ++x) s += rp[x];
    rowsums[((size_t)b * 64 + y) * NC + tid] = s;
}

// ---------- gated global memory: 3 gates in parallel, 4-way split dot ----------
__global__ __launch_bounds__(768) void gates_kernel(
    const float* __restrict__ rowsums,
    const float* __restrict__ wf, const float* __restrict__ bfv,
    const float* __restrict__ wi, const float* __restrict__ biv,
    const float* __restrict__ wc, const float* __restrict__ bcv,
    float* __restrict__ h, const int first) {
    const int b = blockIdx.x;
    const int tid = threadIdx.x;
    const int g = tid >> 8, c = tid & 255;
    __shared__ float sp[256];
    __shared__ float psum[3][256];
    __shared__ float gf[256], gi[256];
    const int y0 = (g == 0) ? 0 : (g == 1) ? 21 : 42;
    const int y1 = (g == 0) ? 21 : (g == 1) ? 42 : 64;
    const float* rs = rowsums + (size_t)b * 64 * NC + c;
    float s = 0.f;
    for (int y = y0; y < y1; ++y) s += rs[y * NC];
    psum[g][c] = s;
    __syncthreads();
    if (g == 0) sp[c] = (psum[0][c] + psum[1][c] + psum[2][c]) * (1.f / 4096.f);
    __syncthreads();
    const float* W  = (g == 0) ? wf  : (g == 1) ? wi  : wc;
    const float* Bv = (g == 0) ? bfv : (g == 1) ? biv : bcv;
    float aA = 0.f, aB = 0.f, aC = 0.f, aD = 0.f;
#pragma unroll 4
    for (int k = 0; k < 256; k += 4) {
        aA = fmaf(sp[k],     W[(size_t)(k)     * NC + c], aA);
        aB = fmaf(sp[k + 1], W[(size_t)(k + 1) * NC + c], aB);
        aC = fmaf(sp[k + 2], W[(size_t)(k + 2) * NC + c], aC);
        aD = fmaf(sp[k + 3], W[(size_t)(k + 3) * NC + c], aD);
    }
    const float a = ((aA + aB) + (aC + aD)) + Bv[c];
    if (g == 0) gf[c] = sigm_(a);
    else if (g == 1) gi[c] = sigm_(a);
    __syncthreads();
    if (g == 2) {
        const float cc = tanhf(a);
        const float hold = first ? 0.f : h[b * NC + c];
        h[b * NC + c] = hold * gf[c] + gi[c] * cc;
    }
}

// ---------- fused step: pipelined 32-wide e-chunks, 512 threads ----------
__global__ __launch_bounds__(512, 4) void step_kernel(
    const ushort* __restrict__ Xg, const ushort* __restrict__ w1t,
    const ushort* __restrict__ w2t, const float* __restrict__ b1,
    const float* __restrict__ b2, const float* __restrict__ uin,
    const ushort* __restrict__ forc, const float* __restrict__ dcoef,
    const float* __restrict__ hbuf, const float* __restrict__ nsc,
    const float* __restrict__ p_logdt, const float* __restrict__ p_am,
    const float* __restrict__ p_af, const int do_norm,
    float* __restrict__ uout, ushort* __restrict__ Xout,
    float* __restrict__ rowsums) {
    __shared__ __align__(16) char pool[75776];
    ushort* Xs  = (ushort*)pool;                 // [64px][256c] swizzled      (32KB)
    ushort* WAu = (ushort*)(pool + 32768);       // w1 chunk [32e][256c] swz   (16KB)
    ushort* WBu = (ushort*)(pool + 49152);       // w2 chunk [256c][32e] swz   (16KB, LINEAR dest)
    ushort* Hsu = (ushort*)(pool + 65536);       // Hs dbuf 2x[64px][40e-pad]  (10KB, ds_write)

    const int tid = threadIdx.x;
    const int wv = tid >> 6, lane = tid & 63;
    const int r16 = lane & 15, kg = lane >> 4;
    const int work = (blockIdx.x & 7) * 64 + (blockIdx.x >> 3);   // XCD swizzle
    const int b = work >> 6, y = work & 63;
    const int m0 = work * 64;

    // ---- initial stages: X tile + w1 chunk 0 (all linear LDS dests) ----
#pragma unroll
    for (int i = 0; i < 4; ++i) {
        const int idx = i * 512 + tid, row = idx >> 5, s = idx & 31;
        gload16(Xg + (size_t)(m0 + row) * NC + ((s ^ (row & 7)) << 3), Xs + idx * 8);
    }
#pragma unroll
    for (int i = 0; i < 2; ++i) {
        const int idx = i * 512 + tid, row = idx >> 5, s = idx & 31;
        gload16(w1t + (size_t)row * NC + ((s ^ (row & 7)) << 3), WAu + idx * 8);
    }

    f32x4 acc2[2][4];   // [ct][p]; wave's c-slice = wv*32
#pragma unroll
    for (int ct = 0; ct < 2; ++ct)
#pragma unroll
        for (int p = 0; p < 4; ++p) acc2[ct][p] = (f32x4){0.f, 0.f, 0.f, 0.f};

    const int eh = wv >> 2, pq = wv & 3;   // GEMM1 wave role: e-half, px-quadrant
    __syncthreads();                       // Xs + WA(0) ready

    for (int ec = 0; ec < 16; ++ec) {
        // stage w2 chunk ec -> WB: LINEAR dest (idx*16B), inverse-swz SOURCE (rule #21)
#pragma unroll
        for (int i = 0; i < 2; ++i) {
            const int idx = i * 512 + tid, row = idx >> 2, s = idx & 3;
            const int sc = (s ^ ((row >> 1) & 3)) << 3;
            gload16(w2t + (size_t)row * NE + ec * 32 + sc, WBu + idx * 8);
        }
        // GEMM1: D1[e][px] from WA x Xs
        f32x4 acc1 = (f32x4){0.f, 0.f, 0.f, 0.f};
        const int rA = eh * 16 + r16, rB = pq * 16 + r16;
#pragma unroll
        for (int kk = 0; kk < 8; ++kk) {
            const int g = kk * 4 + kg;
            const bfrag8 a = *(const bfrag8*)(WAu + rA * 256 + ((g ^ (rA & 7)) << 3));
            const bfrag8 bb = *(const bfrag8*)(Xs + rB * 256 + ((g ^ (rB & 7)) << 3));
            acc1 = __builtin_amdgcn_mfma_f32_16x16x32_bf16(a, bb, acc1, 0, 0, 0);
        }
        // GELU -> Hs[ec&1] (regular ds_write, padded stride OK)
        ushort* Hc = Hsu + (ec & 1) * 2560;
        {
            const int el = eh * 16 + kg * 4;
            const float4 b1v = *(const float4*)(b1 + ec * 32 + el);
            ushort4 hv;
            hv.x = f2bf(gelu_(acc1[0] + b1v.x));
            hv.y = f2bf(gelu_(acc1[1] + b1v.y));
            hv.z = f2bf(gelu_(acc1[2] + b1v.z));
            hv.w = f2bf(gelu_(acc1[3] + b1v.w));
            *(ushort4*)(Hc + (pq * 16 + r16) * 40 + el) = hv;
        }
        __syncthreads();   // B1: WB loads drained (hidden under G1+GELU); Hs visible; WA free
        if (ec < 15) {     // stage w1 chunk ec+1 -> WA (drains at B2, hidden under G2)
#pragma unroll
            for (int i = 0; i < 2; ++i) {
                const int idx = i * 512 + tid, row = idx >> 5, s = idx & 31;
                gload16(w1t + (size_t)((ec + 1) * 32 + row) * NC + ((s ^ (row & 7)) << 3),
                        WAu + idx * 8);
            }
        }
        // GEMM2: react[c][px] += WB x Hs (WB read with matching swizzle)
#pragma unroll
        for (int ct = 0; ct < 2; ++ct) {
            const int rowA = wv * 32 + ct * 16 + r16;
            const bfrag8 a2 = *(const bfrag8*)(WBu + rowA * 32 + ((kg ^ ((rowA >> 1) & 3)) << 3));
#pragma unroll
            for (int p = 0; p < 4; ++p) {
                const bfrag8 bf2 = *(const bfrag8*)(Hc + (p * 16 + r16) * 40 + kg * 8);
                acc2[ct][p] = __builtin_amdgcn_mfma_f32_16x16x32_bf16(a2, bf2, acc2[ct][p], 0, 0, 0);
            }
        }
        __syncthreads();   // B2: WA(ec+1) loads drained; WB free for next stage
    }

    // ---- epilogue ----
    float* trh = (float*)pool;                     // [128][68] f32 (half of c)
    float* su  = (float*)(pool + 34816);           // [128][68] f32 (u_old half)
    const int eg2 = tid >> 4, pg = tid & 15, x0p = pg * 4;
    const float dt = fminf(fmaxf(expf(p_logdt[0]), 0.01f), 0.3f);
    const float am = p_am[0], afc = p_af[0];
    const float* ub = uin + (size_t)b * NC * NHW;
    const ushort* frow = forc + (size_t)b * NC * NHW + (size_t)y * NW;

    float unew[2][4][4];   // [h2][jc][ip]

#pragma unroll
    for (int h2 = 0; h2 < 2; ++h2) {
        __syncthreads();   // GEMM done / prev-half trh+su reads done
        if ((wv >> 2) == h2) {
            // lane: c_rel = (wv&3)*32 + ct*16 + kg*4 + j ; px = p*16 + r16
#pragma unroll
            for (int ct = 0; ct < 2; ++ct)
#pragma unroll
                for (int p = 0; p < 4; ++p)
#pragma unroll
                    for (int j = 0; j < 4; ++j)
                        trh[((wv & 3) * 32 + ct * 16 + kg * 4 + j) * 68 + p * 16 + r16] =
                            acc2[ct][p][j];
        }
#pragma unroll
        for (int i = 0; i < 4; ++i) {   // stage u_old half [128c][64px]
            const int idx = i * 512 + tid;
            const int r = idx >> 4, q = (idx & 15) * 4;
            *(float4*)&su[r * 68 + q] =
                *(const float4*)(ub + (size_t)(h2 * 128 + r) * NHW + (size_t)y * NW + q);
        }
        __syncthreads();   // trh + su ready
#pragma unroll
        for (int jc = 0; jc < 4; ++jc) {
            const int crel = eg2 * 4 + jc;
            const int c = h2 * 128 + crel;
            const float co0 = dcoef[c];
            const float co1 = dcoef[NC + c];
            const float co2 = dcoef[2 * NC + c];
            const float hterm = am * hbuf[b * NC + c];
            const float b2v = b2[c];
            const float* up = ub + (size_t)c * NHW;

            float ym[6][4];
            const int dy[6] = {-1, 1, -2, 2, -4, 4};
#pragma unroll
            for (int n = 0; n < 6; ++n) {
                int ry = y + dy[n];
                ry = ry < 0 ? -ry : (ry > 63 ? 126 - ry : ry);
                const float4 t = *reinterpret_cast<const float4*>(up + (size_t)ry * NW + x0p);
                ym[n][0] = t.x; ym[n][1] = t.y; ym[n][2] = t.z; ym[n][3] = t.w;
            }
            const uint2 fr = *reinterpret_cast<const uint2*>(frow + (size_t)c * NHW + x0p);
            float fv[4];
            fv[0] = bf2f((ushort)(fr.x & 0xffff));
            fv[1] = bf2f((ushort)(fr.x >> 16));
            fv[2] = bf2f((ushort)(fr.y & 0xffff));
            fv[3] = bf2f((ushort)(fr.y >> 16));
            const f32x4 rv = *reinterpret_cast<const f32x4*>(&trh[crel * 68 + x0p]);
#pragma unroll
            for (int ip = 0; ip < 4; ++ip) {
                const int x = x0p + ip;
                const float uc = su[crel * 68 + x];
                int xm, xp2;
                float dsum = 0.f, lap;
                xm = x - 1; xm = xm < 0 ? -xm : xm;
                xp2 = x + 1; xp2 = xp2 > 63 ? 126 - xp2 : xp2;
                lap = su[crel * 68 + xm] + su[crel * 68 + xp2] + ym[0][ip] + ym[1][ip] - 4.f * uc;
                dsum = fmaf(co0, lap, dsum);
                xm = x - 2; xm = xm < 0 ? -xm : xm;
                xp2 = x + 2; xp2 = xp2 > 63 ? 126 - xp2 : xp2;
                lap = su[crel * 68 + xm] + su[crel * 68 + xp2] + ym[2][ip] + ym[3][ip] - 4.f * uc;
                dsum = fmaf(co1, lap, dsum);
                xm = x - 4; xm = xm < 0 ? -xm : xm;
                xp2 = x + 4; xp2 = xp2 > 63 ? 126 - xp2 : xp2;
                lap = su[crel * 68 + xm] + su[crel * 68 + xp2] + ym[4][ip] + ym[5][ip] - 4.f * uc;
                dsum = fmaf(co2, lap, dsum);

                const float du_ = dsum + rv[ip] + b2v + hterm + afc * fv[ip];
                unew[h2][jc][ip] = uc + dt * du_;
            }
        }
    }
    __syncthreads();   // trh/su dead

    // ---- RMSNorm ----
    float* redc   = (float*)(pool + 34816);        // [32][68]
    float* inv64p = (float*)(pool + 43520);        // [64]
    if (do_norm) {
        float ps[4] = {0.f, 0.f, 0.f, 0.f};
#pragma unroll
        for (int h2 = 0; h2 < 2; ++h2)
#pragma unroll
            for (int jc = 0; jc < 4; ++jc)
#pragma unroll
                for (int ip = 0; ip < 4; ++ip)
                    ps[ip] = fmaf(unew[h2][jc][ip], unew[h2][jc][ip], ps[ip]);
        *reinterpret_cast<f32x4*>(&redc[eg2 * 68 + x0p]) = (f32x4){ps[0], ps[1], ps[2], ps[3]};
        __syncthreads();
        if (tid < 64) {
            float s = 0.f;
#pragma unroll
            for (int g = 0; g < 32; ++g) s += redc[g * 68 + tid];
            inv64p[tid] = 1.f / (sqrtf(s) * 0.0625f + 1e-6f);
        }
    }
    __syncthreads();   // inv64 ready; trh region free for xs

    // ---- store u_new + LDS transpose for Xout + rowsums ----
    ushort* xs = (ushort*)pool;                    // [64][270] ushort (34560 B)
    float* sums = (float*)(pool + 52224);          // [256][17]
    float persum[2][4];
    float* uob = uout + (size_t)b * NC * NHW + (size_t)y * NW;
#pragma unroll
    for (int h2 = 0; h2 < 2; ++h2) {
        float vsc[4][4];   // [jc][ip]
#pragma unroll
        for (int jc = 0; jc < 4; ++jc) {
            const int c = h2 * 128 + eg2 * 4 + jc;
            const float ns = do_norm ? nsc[c] : 1.f;
#pragma unroll
            for (int ip = 0; ip < 4; ++ip) {
                float v = unew[h2][jc][ip];
                if (do_norm) v *= inv64p[x0p + ip] * ns;
                vsc[jc][ip] = v;
            }
            persum[h2][jc] = vsc[jc][0] + vsc[jc][1] + vsc[jc][2] + vsc[jc][3];
            float4 o; o.x = vsc[jc][0]; o.y = vsc[jc][1]; o.z = vsc[jc][2]; o.w = vsc[jc][3];
            *reinterpret_cast<float4*>(uob + (size_t)c * NHW + x0p) = o;
        }
#pragma unroll
        for (int ip = 0; ip < 4; ++ip) {
            ushort4 xv;
            xv.x = f2bf(vsc[0][ip]);
            xv.y = f2bf(vsc[1][ip]);
            xv.z = f2bf(vsc[2][ip]);
            xv.w = f2bf(vsc[3][ip]);
            *(ushort4*)(xs + (x0p + ip) * 270 + h2 * 128 + eg2 * 4) = xv;
        }
    }
#pragma unroll
    for (int h2 = 0; h2 < 2; ++h2)
#pragma unroll
        for (int jc = 0; jc < 4; ++jc)
            sums[(h2 * 128 + eg2 * 4 + jc) * 17 + pg] = persum[h2][jc];
    __syncthreads();   // xs + sums ready
    ushort* Xp = Xout + (size_t)m0 * NC;
#pragma unroll
    for (int r = 0; r < 8; ++r) {
        const int row = wv * 8 + r;
        *reinterpret_cast<uint2*>(Xp + (size_t)row * NC + lane * 4) =
            *reinterpret_cast<const uint2*>(&xs[row * 270 + lane * 4]);
    }
    if (tid < 256) {
        float s = 0.f;
#pragma unroll
        for (int g = 0; g < 16; ++g) s += sums[tid * 17 + g];
        rowsums[((size_t)b * 64 + y) * NC + tid] = s;
    }
}

extern "C" void kernel_launch(void* const* d_in, const int* in_sizes, int n_in,
                              void* d_out, int out_size, void* d_ws, size_t ws_size,
                              hipStream_t stream) {
    (void)in_sizes; (void)n_in; (void)out_size; (void)ws_size;
    const float* u0      = (const float*)d_in[0];
    const float* forcing = (const float*)d_in[1];
    const float* dlog    = (const float*)d_in[2];
    const float* w1      = (const float*)d_in[3];
    const float* b1      = (const float*)d_in[4];
    const float* w2      = (const float*)d_in[5];
    const float* b2      = (const float*)d_in[6];
    const float* wf      = (const float*)d_in[7];
    const float* bfv     = (const float*)d_in[8];
    const float* wi      = (const float*)d_in[9];
    const float* biv     = (const float*)d_in[10];
    const float* wc      = (const float*)d_in[11];
    const float* bcv     = (const float*)d_in[12];
    const float* nsc     = (const float*)d_in[13];
    const float* p_logdt = (const float*)d_in[14];
    const float* p_am    = (const float*)d_in[15];
    const float* p_af    = (const float*)d_in[16];

    float* uout = (float*)d_out;

    char* w = (char*)d_ws;
    float*  uA     = (float*)w;   w += (size_t)NB * NC * NHW * 4;   // 33.5 MB
    ushort* X      = (ushort*)w;  w += (size_t)NB * NHW * NC * 2;   // 16.8 MB
    ushort* forc   = (ushort*)w;  w += (size_t)NB * NC * NHW * 2;   // 16.8 MB
    ushort* w1t    = (ushort*)w;  w += (size_t)NE * NC * 2;
    ushort* w2t    = (ushort*)w;  w += (size_t)NC * NE * 2;
    float* rowsums = (float*)w;   w += (size_t)NB * NH * NC * 4;    // 512 KB
    float* hbuf    = (float*)w;   w += (size_t)NB * NC * 4;
    float* dcoef   = (float*)w;   w += (size_t)3 * NC * 4;

    wt_kernel<<<769, 256, 0, stream>>>(w1, w2, dlog, w1t, w2t, dcoef);
    fconv_kernel<<<4096, 256, 0, stream>>>(forcing, forc);
    x0_kernel<<<NB * NH, 256, 0, stream>>>(u0, X, rowsums);

    const float* src = u0;
    for (int t = 0; t < STEPS; ++t) {
        float* dst = (t & 1) ? uout : uA;    // t=5 -> uout
        gates_kernel<<<NB, 768, 0, stream>>>(rowsums, wf, bfv, wi, biv, wc, bcv, hbuf, t == 0);
        step_kernel<<<NB * NH, 512, 0, stream>>>(X, w1t, w2t, b1, b2, src, forc, dcoef,
                                                 hbuf, nsc, p_logdt, p_am, p_af,
                                                 ((t + 1) % 2) == 0, dst, X, rowsums);
        src = dst;
    }
}

// Round 9
// 566.544 us; speedup vs baseline: 1.2953x; 1.0175x over previous
//
#include <hip/hip_runtime.h>
#include <math.h>

constexpr int NB = 8, NC = 256, NE = 512, NH = 64, NW = 64, NHW = NH * NW;
constexpr int STEPS = 6;

typedef short bfrag8 __attribute__((ext_vector_type(8)));   // 8 bf16 in 4 VGPRs
typedef float f32x4 __attribute__((ext_vector_type(4)));

__device__ __forceinline__ float sigm_(float x) { return 1.f / (1.f + expf(-x)); }
// tanh-form GELU, overflow-safe: x * sigmoid(1.5957691(x + 0.044715 x^3))
__device__ __forceinline__ float gelu_(float x) {
    const float t2 = fmaf(0.0713548162f * x, x * x, 1.5957691216f * x);
    return x / (1.f + __expf(-t2));
}
__device__ __forceinline__ ushort f2bf(float f) {
    unsigned u = __builtin_bit_cast(unsigned, f);
    unsigned r = (u + 0x7fffu + ((u >> 16) & 1u)) >> 16;   // RNE
    return (ushort)r;
}
__device__ __forceinline__ float bf2f(ushort us) {
    return __builtin_bit_cast(float, (unsigned)us << 16);
}
__device__ __forceinline__ void gload16(const void* g, void* l) {
    __builtin_amdgcn_global_load_lds((const __attribute__((address_space(1))) void*)g,
                                     (__attribute__((address_space(3))) void*)l, 16, 0, 0);
}

// ---------- prologue: bf16 weights (w1t, w2t, gates) + stencil coefficients ----------
__global__ void wt_kernel(const float* __restrict__ w1, const float* __restrict__ w2,
                          const float* __restrict__ dlog,
                          const float* __restrict__ wf, const float* __restrict__ wi,
                          const float* __restrict__ wc,
                          ushort* __restrict__ w1t, ushort* __restrict__ w2t,
                          float* __restrict__ dcoef, ushort* __restrict__ wgb) {
    const int bid = blockIdx.x, tid = threadIdx.x;
    if (bid < NE) {                       // w1t[e][c] = w1[c][e]
        w1t[bid * NC + tid] = f2bf(w1[(size_t)tid * NE + bid]);
    } else if (bid < NE + NC) {           // w2t[c][e] = w2[e][c]
        const int c = bid - NE;
        for (int e = tid; e < NE; e += 256)
            w2t[c * NE + e] = f2bf(w2[(size_t)e * NC + c]);
    } else if (bid == NE + NC) {
#pragma unroll
        for (int i = 0; i < 3; ++i)
            dcoef[i * NC + tid] = 0.25f * sigm_(dlog[i * NC + tid]);
    } else {                              // gate weights -> bf16, same [k][c] layout
        const int k = bid - (NE + NC + 1);
        wgb[(0 * NC + k) * NC + tid] = f2bf(wf[(size_t)k * NC + tid]);
        wgb[(1 * NC + k) * NC + tid] = f2bf(wi[(size_t)k * NC + tid]);
        wgb[(2 * NC + k) * NC + tid] = f2bf(wc[(size_t)k * NC + tid]);
    }
}

// ---------- prologue: forcing -> bf16 ----------
__global__ void fconv_kernel(const float* __restrict__ fin, ushort* __restrict__ fout) {
    const size_t i8 = ((size_t)blockIdx.x * 256 + threadIdx.x) * 8;
    const float4 a = *reinterpret_cast<const float4*>(fin + i8);
    const float4 b = *reinterpret_cast<const float4*>(fin + i8 + 4);
    uint4 o;
    o.x = (unsigned)f2bf(a.x) | ((unsigned)f2bf(a.y) << 16);
    o.y = (unsigned)f2bf(a.z) | ((unsigned)f2bf(a.w) << 16);
    o.z = (unsigned)f2bf(b.x) | ((unsigned)f2bf(b.y) << 16);
    o.w = (unsigned)f2bf(b.z) | ((unsigned)f2bf(b.w) << 16);
    *reinterpret_cast<uint4*>(fout + i8) = o;
}

// ---------- prologue: initial per-row channel sums from u0 ----------
__global__ __launch_bounds__(256) void rs0_kernel(const float* __restrict__ u,
                                                  float* __restrict__ rowsums) {
    const int b = blockIdx.x >> 6, y = blockIdx.x & 63;
    const int c = threadIdx.x;
    const float* rp = u + ((size_t)b * NC + c) * NHW + (size_t)y * NW;
    float s = 0.f;
#pragma unroll
    for (int i = 0; i < 16; ++i) {
        const float4 v = *reinterpret_cast<const float4*>(rp + i * 4);
        s += (v.x + v.y) + (v.z + v.w);
    }
    rowsums[((size_t)b * 64 + y) * NC + c] = s;
}

// ---------- gated global memory: 3 gates in parallel, bf16 weights ----------
__global__ __launch_bounds__(768) void gates_kernel(
    const float* __restrict__ rowsums, const ushort* __restrict__ wgb,
    const float* __restrict__ bfv, const float* __restrict__ biv,
    const float* __restrict__ bcv,
    float* __restrict__ h, const int first) {
    const int b = blockIdx.x;
    const int tid = threadIdx.x;
    const int g = tid >> 8, c = tid & 255;
    __shared__ float sp[256];
    __shared__ float psum[3][256];
    __shared__ float gf[256], gi[256];
    const int y0 = (g == 0) ? 0 : (g == 1) ? 21 : 42;
    const int y1 = (g == 0) ? 21 : (g == 1) ? 42 : 64;
    const float* rs = rowsums + (size_t)b * 64 * NC + c;
    float s = 0.f;
    for (int y = y0; y < y1; ++y) s += rs[y * NC];
    psum[g][c] = s;
    __syncthreads();
    if (g == 0) sp[c] = (psum[0][c] + psum[1][c] + psum[2][c]) * (1.f / 4096.f);
    __syncthreads();
    const ushort* W16 = wgb + (size_t)g * NC * NC;
    const float* Bv = (g == 0) ? bfv : (g == 1) ? biv : bcv;
    float aA = 0.f, aB = 0.f, aC = 0.f, aD = 0.f;
#pragma unroll 4
    for (int k = 0; k < 256; k += 4) {
        aA = fmaf(sp[k],     bf2f(W16[(k)     * NC + c]), aA);
        aB = fmaf(sp[k + 1], bf2f(W16[(k + 1) * NC + c]), aB);
        aC = fmaf(sp[k + 2], bf2f(W16[(k + 2) * NC + c]), aC);
        aD = fmaf(sp[k + 3], bf2f(W16[(k + 3) * NC + c]), aD);
    }
    const float a = ((aA + aB) + (aC + aD)) + Bv[c];
    if (g == 0) gf[c] = sigm_(a);
    else if (g == 1) gi[c] = sigm_(a);
    __syncthreads();
    if (g == 2) {
        const float cc = tanhf(a);
        const float hold = first ? 0.f : h[b * NC + c];
        h[b * NC + c] = hold * gf[c] + gi[c] * cc;
    }
}

// ---------- fused step: stages Xs from u directly; pipelined 32-wide e-chunks ----------
__global__ __launch_bounds__(512, 4) void step_kernel(
    const ushort* __restrict__ w1t, const ushort* __restrict__ w2t,
    const float* __restrict__ b1, const float* __restrict__ b2,
    const float* __restrict__ uin, const ushort* __restrict__ forc,
    const float* __restrict__ dcoef, const float* __restrict__ hbuf,
    const float* __restrict__ nsc, const float* __restrict__ p_logdt,
    const float* __restrict__ p_am, const float* __restrict__ p_af,
    const int do_norm, float* __restrict__ uout, float* __restrict__ rowsums) {
    __shared__ __align__(16) char pool[75776];
    ushort* Xs  = (ushort*)pool;                 // [64px][256c] swizzled      (32KB)
    ushort* WAu = (ushort*)(pool + 32768);       // w1 chunk [32e][256c] swz   (16KB)
    ushort* WBu = (ushort*)(pool + 49152);       // w2 chunk [256c][32e] swz   (16KB)
    ushort* Hsu = (ushort*)(pool + 65536);       // Hs dbuf 2x[64px][40e-pad]  (10KB)

    const int tid = threadIdx.x;
    const int wv = tid >> 6, lane = tid & 63;
    const int r16 = lane & 15, kg = lane >> 4;
    const int work = (blockIdx.x & 7) * 64 + (blockIdx.x >> 3);   // XCD swizzle
    const int b = work >> 6, y = work & 63;

    const float* ub = uin + (size_t)b * NC * NHW;
    const float* uyb = ub + (size_t)y * NW;

    // ---- stage w1 chunk 0 (gload) + Xs from u row y (reg 4x4 transpose -> ds_write) ----
#pragma unroll
    for (int i = 0; i < 2; ++i) {
        const int idx = i * 512 + tid, row = idx >> 5, s = idx & 31;
        gload16(w1t + (size_t)row * NC + ((s ^ (row & 7)) << 3), WAu + idx * 8);
    }
#pragma unroll
    for (int tt = 0; tt < 2; ++tt) {
        const int id = tt * 512 + tid;
        const int pg_ = id & 15, cg_ = id >> 4;       // cg_ 0..63
        const int px0 = pg_ * 4, c0 = cg_ * 4;
        const float4 r0 = *(const float4*)(uyb + (size_t)(c0 + 0) * NHW + px0);
        const float4 r1 = *(const float4*)(uyb + (size_t)(c0 + 1) * NHW + px0);
        const float4 r2 = *(const float4*)(uyb + (size_t)(c0 + 2) * NHW + px0);
        const float4 r3 = *(const float4*)(uyb + (size_t)(c0 + 3) * NHW + px0);
        const int slot = c0 >> 3, sub = c0 & 7;       // sub in {0,4}
        const float a0[4] = {r0.x, r0.y, r0.z, r0.w};
        const float a1[4] = {r1.x, r1.y, r1.z, r1.w};
        const float a2[4] = {r2.x, r2.y, r2.z, r2.w};
        const float a3[4] = {r3.x, r3.y, r3.z, r3.w};
#pragma unroll
        for (int i2 = 0; i2 < 4; ++i2) {
            const int px = px0 + i2;
            ushort4 xv;
            xv.x = f2bf(a0[i2]);
            xv.y = f2bf(a1[i2]);
            xv.z = f2bf(a2[i2]);
            xv.w = f2bf(a3[i2]);
            *(ushort4*)(Xs + px * 256 + ((slot ^ (px & 7)) << 3) + sub) = xv;
        }
    }

    f32x4 acc2[2][4];   // [ct][p]; wave's c-slice = wv*32
#pragma unroll
    for (int ct = 0; ct < 2; ++ct)
#pragma unroll
        for (int p = 0; p < 4; ++p) acc2[ct][p] = (f32x4){0.f, 0.f, 0.f, 0.f};

    const int eh = wv >> 2, pq = wv & 3;   // GEMM1 wave role: e-half, px-quadrant
    __syncthreads();                       // Xs (ds_write) + WA(0) (gload) ready

    for (int ec = 0; ec < 16; ++ec) {
        // stage w2 chunk ec -> WB: LINEAR dest, inverse-swz SOURCE (rule #21)
#pragma unroll
        for (int i = 0; i < 2; ++i) {
            const int idx = i * 512 + tid, row = idx >> 2, s = idx & 3;
            const int sc = (s ^ ((row >> 1) & 3)) << 3;
            gload16(w2t + (size_t)row * NE + ec * 32 + sc, WBu + idx * 8);
        }
        // GEMM1: D1[e][px] from WA x Xs
        f32x4 acc1 = (f32x4){0.f, 0.f, 0.f, 0.f};
        const int rA = eh * 16 + r16, rB = pq * 16 + r16;
#pragma unroll
        for (int kk = 0; kk < 8; ++kk) {
            const int g = kk * 4 + kg;
            const bfrag8 a = *(const bfrag8*)(WAu + rA * 256 + ((g ^ (rA & 7)) << 3));
            const bfrag8 bb = *(const bfrag8*)(Xs + rB * 256 + ((g ^ (rB & 7)) << 3));
            acc1 = __builtin_amdgcn_mfma_f32_16x16x32_bf16(a, bb, acc1, 0, 0, 0);
        }
        // GELU -> Hs[ec&1]
        ushort* Hc = Hsu + (ec & 1) * 2560;
        {
            const int el = eh * 16 + kg * 4;
            const float4 b1v = *(const float4*)(b1 + ec * 32 + el);
            ushort4 hv;
            hv.x = f2bf(gelu_(acc1[0] + b1v.x));
            hv.y = f2bf(gelu_(acc1[1] + b1v.y));
            hv.z = f2bf(gelu_(acc1[2] + b1v.z));
            hv.w = f2bf(gelu_(acc1[3] + b1v.w));
            *(ushort4*)(Hc + (pq * 16 + r16) * 40 + el) = hv;
        }
        __syncthreads();   // B1: WB drained (hidden under G1+GELU); Hs visible; WA free
        if (ec < 15) {     // stage w1 chunk ec+1 -> WA (drains at B2, hidden under G2)
#pragma unroll
            for (int i = 0; i < 2; ++i) {
                const int idx = i * 512 + tid, row = idx >> 5, s = idx & 31;
                gload16(w1t + (size_t)((ec + 1) * 32 + row) * NC + ((s ^ (row & 7)) << 3),
                        WAu + idx * 8);
            }
        }
        // GEMM2: react[c][px] += WB x Hs
#pragma unroll
        for (int ct = 0; ct < 2; ++ct) {
            const int rowA = wv * 32 + ct * 16 + r16;
            const bfrag8 a2 = *(const bfrag8*)(WBu + rowA * 32 + ((kg ^ ((rowA >> 1) & 3)) << 3));
#pragma unroll
            for (int p = 0; p < 4; ++p) {
                const bfrag8 bf2 = *(const bfrag8*)(Hc + (p * 16 + r16) * 40 + kg * 8);
                acc2[ct][p] = __builtin_amdgcn_mfma_f32_16x16x32_bf16(a2, bf2, acc2[ct][p], 0, 0, 0);
            }
        }
        __syncthreads();   // B2: WA(ec+1) drained; WB free for next stage
    }

    // ---- epilogue ----
    float* trh = (float*)pool;                     // [128][68] f32 (half of c)
    float* su  = (float*)(pool + 34816);           // [128][68] f32 (u_old half)
    const int eg2 = tid >> 4, pg = tid & 15, x0p = pg * 4;
    const float dt = fminf(fmaxf(expf(p_logdt[0]), 0.01f), 0.3f);
    const float am = p_am[0], afc = p_af[0];
    const ushort* frow = forc + (size_t)b * NC * NHW + (size_t)y * NW;

    float unew[2][4][4];   // [h2][jc][ip]

#pragma unroll
    for (int h2 = 0; h2 < 2; ++h2) {
        __syncthreads();   // GEMM done / prev-half trh+su reads done
        if ((wv >> 2) == h2) {
#pragma unroll
            for (int ct = 0; ct < 2; ++ct)
#pragma unroll
                for (int p = 0; p < 4; ++p)
#pragma unroll
                    for (int j = 0; j < 4; ++j)
                        trh[((wv & 3) * 32 + ct * 16 + kg * 4 + j) * 68 + p * 16 + r16] =
                            acc2[ct][p][j];
        }
#pragma unroll
        for (int i = 0; i < 4; ++i) {   // stage u_old half [128c][64px]
            const int idx = i * 512 + tid;
            const int r = idx >> 4, q = (idx & 15) * 4;
            *(float4*)&su[r * 68 + q] =
                *(const float4*)(ub + (size_t)(h2 * 128 + r) * NHW + (size_t)y * NW + q);
        }
        __syncthreads();   // trh + su ready
#pragma unroll
        for (int jc = 0; jc < 4; ++jc) {
            const int crel = eg2 * 4 + jc;
            const int c = h2 * 128 + crel;
            const float co0 = dcoef[c];
            const float co1 = dcoef[NC + c];
            const float co2 = dcoef[2 * NC + c];
            const float hterm = am * hbuf[b * NC + c];
            const float b2v = b2[c];
            const float* up = ub + (size_t)c * NHW;

            float ym[6][4];
            const int dy[6] = {-1, 1, -2, 2, -4, 4};
#pragma unroll
            for (int n = 0; n < 6; ++n) {
                int ry = y + dy[n];
                ry = ry < 0 ? -ry : (ry > 63 ? 126 - ry : ry);
                const float4 t = *reinterpret_cast<const float4*>(up + (size_t)ry * NW + x0p);
                ym[n][0] = t.x; ym[n][1] = t.y; ym[n][2] = t.z; ym[n][3] = t.w;
            }
            const uint2 fr = *reinterpret_cast<const uint2*>(frow + (size_t)c * NHW + x0p);
            float fv[4];
            fv[0] = bf2f((ushort)(fr.x & 0xffff));
            fv[1] = bf2f((ushort)(fr.x >> 16));
            fv[2] = bf2f((ushort)(fr.y & 0xffff));
            fv[3] = bf2f((ushort)(fr.y >> 16));
            const f32x4 rv = *reinterpret_cast<const f32x4*>(&trh[crel * 68 + x0p]);
#pragma unroll
            for (int ip = 0; ip < 4; ++ip) {
                const int x = x0p + ip;
                const float uc = su[crel * 68 + x];
                int xm, xp2;
                float dsum = 0.f, lap;
                xm = x - 1; xm = xm < 0 ? -xm : xm;
                xp2 = x + 1; xp2 = xp2 > 63 ? 126 - xp2 : xp2;
                lap = su[crel * 68 + xm] + su[crel * 68 + xp2] + ym[0][ip] + ym[1][ip] - 4.f * uc;
                dsum = fmaf(co0, lap, dsum);
                xm = x - 2; xm = xm < 0 ? -xm : xm;
                xp2 = x + 2; xp2 = xp2 > 63 ? 126 - xp2 : xp2;
                lap = su[crel * 68 + xm] + su[crel * 68 + xp2] + ym[2][ip] + ym[3][ip] - 4.f * uc;
                dsum = fmaf(co1, lap, dsum);
                xm = x - 4; xm = xm < 0 ? -xm : xm;
                xp2 = x + 4; xp2 = xp2 > 63 ? 126 - xp2 : xp2;
                lap = su[crel * 68 + xm] + su[crel * 68 + xp2] + ym[4][ip] + ym[5][ip] - 4.f * uc;
                dsum = fmaf(co2, lap, dsum);

                const float du_ = dsum + rv[ip] + b2v + hterm + afc * fv[ip];
                unew[h2][jc][ip] = uc + dt * du_;
            }
        }
    }
    __syncthreads();   // trh/su dead

    // ---- RMSNorm ----
    float* redc   = (float*)(pool + 34816);        // [32][68]
    float* inv64p = (float*)(pool + 43520);        // [64]
    if (do_norm) {
        float ps[4] = {0.f, 0.f, 0.f, 0.f};
#pragma unroll
        for (int h2 = 0; h2 < 2; ++h2)
#pragma unroll
            for (int jc = 0; jc < 4; ++jc)
#pragma unroll
                for (int ip = 0; ip < 4; ++ip)
                    ps[ip] = fmaf(unew[h2][jc][ip], unew[h2][jc][ip], ps[ip]);
        *reinterpret_cast<f32x4*>(&redc[eg2 * 68 + x0p]) = (f32x4){ps[0], ps[1], ps[2], ps[3]};
        __syncthreads();
        if (tid < 64) {
            float s = 0.f;
#pragma unroll
            for (int g = 0; g < 32; ++g) s += redc[g * 68 + tid];
            inv64p[tid] = 1.f / (sqrtf(s) * 0.0625f + 1e-6f);
        }
    }
    __syncthreads();   // inv64 ready

    // ---- store u_new (fp32, channel-major) + rowsums ----
    float* sums = (float*)(pool + 52224);          // [256][17]
    float persum[2][4];
    float* uob = uout + (size_t)b * NC * NHW + (size_t)y * NW;
#pragma unroll
    for (int h2 = 0; h2 < 2; ++h2) {
#pragma unroll
        for (int jc = 0; jc < 4; ++jc) {
            const int c = h2 * 128 + eg2 * 4 + jc;
            const float ns = do_norm ? nsc[c] : 1.f;
            float vv[4];
#pragma unroll
            for (int ip = 0; ip < 4; ++ip) {
                float v = unew[h2][jc][ip];
                if (do_norm) v *= inv64p[x0p + ip] * ns;
                vv[ip] = v;
            }
            persum[h2][jc] = (vv[0] + vv[1]) + (vv[2] + vv[3]);
            float4 o; o.x = vv[0]; o.y = vv[1]; o.z = vv[2]; o.w = vv[3];
            *reinterpret_cast<float4*>(uob + (size_t)c * NHW + x0p) = o;
            sums[c * 17 + pg] = persum[h2][jc];
        }
    }
    __syncthreads();   // sums ready
    if (tid < 256) {
        float s = 0.f;
#pragma unroll
        for (int g = 0; g < 16; ++g) s += sums[tid * 17 + g];
        rowsums[((size_t)b * 64 + y) * NC + tid] = s;
    }
}

extern "C" void kernel_launch(void* const* d_in, const int* in_sizes, int n_in,
                              void* d_out, int out_size, void* d_ws, size_t ws_size,
                              hipStream_t stream) {
    (void)in_sizes; (void)n_in; (void)out_size; (void)ws_size;
    const float* u0      = (const float*)d_in[0];
    const float* forcing = (const float*)d_in[1];
    const float* dlog    = (const float*)d_in[2];
    const float* w1      = (const float*)d_in[3];
    const float* b1      = (const float*)d_in[4];
    const float* w2      = (const float*)d_in[5];
    const float* b2      = (const float*)d_in[6];
    const float* wf      = (const float*)d_in[7];
    const float* bfv     = (const float*)d_in[8];
    const float* wi      = (const float*)d_in[9];
    const float* biv     = (const float*)d_in[10];
    const float* wc      = (const float*)d_in[11];
    const float* bcv     = (const float*)d_in[12];
    const float* nsc     = (const float*)d_in[13];
    const float* p_logdt = (const float*)d_in[14];
    const float* p_am    = (const float*)d_in[15];
    const float* p_af    = (const float*)d_in[16];

    float* uout = (float*)d_out;

    char* w = (char*)d_ws;
    float*  uA     = (float*)w;   w += (size_t)NB * NC * NHW * 4;   // 33.5 MB
    ushort* forc   = (ushort*)w;  w += (size_t)NB * NC * NHW * 2;   // 16.8 MB
    ushort* w1t    = (ushort*)w;  w += (size_t)NE * NC * 2;
    ushort* w2t    = (ushort*)w;  w += (size_t)NC * NE * 2;
    ushort* wgb    = (ushort*)w;  w += (size_t)3 * NC * NC * 2;     // 384 KB
    float* rowsums = (float*)w;   w += (size_t)NB * NH * NC * 4;    // 512 KB
    float* hbuf    = (float*)w;   w += (size_t)NB * NC * 4;
    float* dcoef   = (float*)w;   w += (size_t)3 * NC * 4;

    wt_kernel<<<NE + NC + 1 + NC, 256, 0, stream>>>(w1, w2, dlog, wf, wi, wc,
                                                    w1t, w2t, dcoef, wgb);
    fconv_kernel<<<4096, 256, 0, stream>>>(forcing, forc);
    rs0_kernel<<<NB * NH, 256, 0, stream>>>(u0, rowsums);

    const float* src = u0;
    for (int t = 0; t < STEPS; ++t) {
        float* dst = (t & 1) ? uout : uA;    // t=5 -> uout
        gates_kernel<<<NB, 768, 0, stream>>>(rowsums, wgb, bfv, biv, bcv, hbuf, t == 0);
        step_kernel<<<NB * NH, 512, 0, stream>>>(w1t, w2t, b1, b2, src, forc, dcoef,
                                                 hbuf, nsc, p_logdt, p_am, p_af,
                                                 ((t + 1) % 2) == 0, dst, rowsums);
        src = dst;
    }
}